// Round 1
// baseline (1237.172 us; speedup 1.0000x reference)
//
#include <hip/hip_runtime.h>
#include <math.h>

// Problem dims
#define B_   32
#define S_   4096
#define H_   512
#define IN_  512
#define ENC_ 1024
#define V_   32000
#define K3H  1536   // 3*H
#define GIN  1536   // IN + ENC

// d_out layout (float offsets), outputs concatenated in return order:
// output [32][32000], new_context [32][1024], hidden_new [2][32][512], attn_weights [32][4096]
#define CTX_OFF  1024000
#define HID_OFF  1056768
#define ATTN_OFF 1089536

// ws layout (float offsets)
#define WS_H0   0
#define WS_H1   16384
#define WS_V    32768
#define WS_CTXP 65536   // 32 b * 8 chunks * 1024 f = 262144 floats

__device__ __forceinline__ float wave_reduce_sum(float v) {
    #pragma unroll
    for (int off = 32; off > 0; off >>= 1) v += __shfl_xor(v, off, 64);
    return v;
}

// ---------------- GRU layer (wave per (b,h) output) ----------------
// CONCAT: input = [x (512) | context (1024)]; else input = xa[b*KIN + k]
template<int KIN, bool CONCAT>
__global__ __launch_bounds__(256) void gru_kernel(
    const float* __restrict__ xa, const float* __restrict__ xb,
    const float* __restrict__ hprev,
    const float* __restrict__ Wih, const float* __restrict__ Whh,
    const float* __restrict__ bih, const float* __restrict__ bhh,
    float* __restrict__ hws, float* __restrict__ hout)
{
    int wid  = blockIdx.x * 4 + (threadIdx.x >> 6);   // 0..16383
    int lane = threadIdx.x & 63;
    int b = wid & 31;          // consecutive waves share weight rows -> L2 hit
    int h = wid >> 5;          // 0..511

    const float* wr = Wih + (size_t)h         * KIN;
    const float* wz = Wih + (size_t)(H_ + h)  * KIN;
    const float* wn = Wih + (size_t)(2*H_ + h)* KIN;
    float pr = 0.f, pz = 0.f, pn = 0.f;
    for (int k = lane; k < KIN; k += 64) {
        float xv;
        if (CONCAT) xv = (k < IN_) ? xa[b*IN_ + k] : xb[b*ENC_ + (k - IN_)];
        else        xv = xa[b*KIN + k];
        pr += xv * wr[k]; pz += xv * wz[k]; pn += xv * wn[k];
    }

    const float* ur = Whh + (size_t)h          * H_;
    const float* uz = Whh + (size_t)(H_ + h)   * H_;
    const float* un = Whh + (size_t)(2*H_ + h) * H_;
    const float* hp = hprev + b * H_;
    float qr = 0.f, qz = 0.f, qn = 0.f;
    for (int k = lane; k < H_; k += 64) {
        float hv = hp[k];
        qr += hv * ur[k]; qz += hv * uz[k]; qn += hv * un[k];
    }

    pr = wave_reduce_sum(pr); pz = wave_reduce_sum(pz); pn = wave_reduce_sum(pn);
    qr = wave_reduce_sum(qr); qz = wave_reduce_sum(qz); qn = wave_reduce_sum(qn);

    if (lane == 0) {
        float r = 1.f / (1.f + expf(-(pr + bih[h]       + qr + bhh[h])));
        float z = 1.f / (1.f + expf(-(pz + bih[H_ + h]  + qz + bhh[H_ + h])));
        float n = tanhf(pn + bih[2*H_ + h] + r * (qn + bhh[2*H_ + h]));
        float hnew = (1.f - z) * n + z * hp[h];
        hws[b*H_ + h]  = hnew;
        hout[b*H_ + h] = hnew;
    }
}

// ---------------- v[b,f] = sum_h h1[b,h] * attn_W[h,f] ----------------
__global__ __launch_bounds__(256) void attn_v_kernel(
    const float* __restrict__ h1, const float* __restrict__ attn_W,
    float* __restrict__ v)
{
    __shared__ float h1s[8 * H_];           // 16 KB: 8 batches of h1
    int bg = blockIdx.x >> 2;               // batch group 0..3 (8 b each)
    int fc = blockIdx.x & 3;                // feature chunk 0..3 (256 f each)
    for (int i = threadIdx.x; i < 8 * H_; i += 256) h1s[i] = h1[bg*8*H_ + i];
    __syncthreads();

    int f = fc * 256 + threadIdx.x;
    float acc[8] = {0.f,0.f,0.f,0.f,0.f,0.f,0.f,0.f};
    for (int hh = 0; hh < H_; ++hh) {
        float w = attn_W[(size_t)hh * ENC_ + f];   // coalesced
        #pragma unroll
        for (int i = 0; i < 8; ++i) acc[i] += h1s[i*H_ + hh] * w;  // LDS broadcast
    }
    #pragma unroll
    for (int i = 0; i < 8; ++i) v[(size_t)(bg*8 + i)*ENC_ + f] = acc[i];
}

// ---------------- energies: e[b,s] = enc[b,s,:] . v[b,:] ----------------
// wave per 4 rows; writes RAW energies into d_out attn_weights region
__global__ __launch_bounds__(256) void energy_kernel(
    const float* __restrict__ enc, const float* __restrict__ v,
    float* __restrict__ e_out)
{
    int wid  = blockIdx.x * 4 + (threadIdx.x >> 6);  // 0..32767
    int lane = threadIdx.x & 63;
    int b  = wid >> 10;
    int s0 = (wid & 1023) * 4;

    const float4* v4 = (const float4*)(v + (size_t)b * ENC_);
    float4 vf[4];
    #pragma unroll
    for (int i = 0; i < 4; ++i) vf[i] = v4[lane + 64*i];

    const float4* er = (const float4*)(enc + ((size_t)b * S_ + s0) * ENC_);
    #pragma unroll
    for (int r = 0; r < 4; ++r) {
        float p = 0.f;
        #pragma unroll
        for (int i = 0; i < 4; ++i) {
            float4 ev = er[(size_t)r*256 + lane + 64*i];   // 1 KB/instr, coalesced
            p += ev.x*vf[i].x + ev.y*vf[i].y + ev.z*vf[i].z + ev.w*vf[i].w;
        }
        p = wave_reduce_sum(p);
        if (lane == 0) e_out[(size_t)b * S_ + s0 + r] = p;
    }
}

// ---------------- softmax in-place over [32][4096] ----------------
__global__ __launch_bounds__(256) void softmax_kernel(float* __restrict__ attnw)
{
    __shared__ float buf[S_];   // 16 KB
    __shared__ float red[4];
    int b = blockIdx.x;
    float* row = attnw + (size_t)b * S_;

    float lmax = -3.0e38f;
    for (int i = threadIdx.x; i < S_; i += 256) {
        float x = row[i]; buf[i] = x; lmax = fmaxf(lmax, x);
    }
    #pragma unroll
    for (int off = 32; off > 0; off >>= 1) lmax = fmaxf(lmax, __shfl_xor(lmax, off, 64));
    if ((threadIdx.x & 63) == 0) red[threadIdx.x >> 6] = lmax;
    __syncthreads();
    float m = fmaxf(fmaxf(red[0], red[1]), fmaxf(red[2], red[3]));

    float lsum = 0.f;
    for (int i = threadIdx.x; i < S_; i += 256) {
        float ex = expf(buf[i] - m); buf[i] = ex; lsum += ex;
    }
    lsum = wave_reduce_sum(lsum);
    __syncthreads();
    if ((threadIdx.x & 63) == 0) red[threadIdx.x >> 6] = lsum;
    __syncthreads();
    float inv = 1.f / (red[0] + red[1] + red[2] + red[3]);
    for (int i = threadIdx.x; i < S_; i += 256) row[i] = buf[i] * inv;
}

// ---------------- context partials: per (b, s-chunk of 512) ----------------
__global__ __launch_bounds__(256) void ctx_partial_kernel(
    const float* __restrict__ enc, const float* __restrict__ attnw,
    float* __restrict__ part)
{
    __shared__ float wts[512];
    int b  = blockIdx.x >> 3;
    int sc = blockIdx.x & 7;
    int s0 = sc * 512;
    for (int i = threadIdx.x; i < 512; i += 256) wts[i] = attnw[(size_t)b*S_ + s0 + i];
    __syncthreads();

    const float4* er = (const float4*)(enc + ((size_t)b * S_ + s0) * ENC_);
    int t = threadIdx.x;                  // owns features 4t..4t+3
    float ax = 0.f, ay = 0.f, az = 0.f, aw = 0.f;
    for (int s = 0; s < 512; ++s) {
        float w = wts[s];                 // LDS broadcast
        float4 ev = er[(size_t)s*256 + t];
        ax += w*ev.x; ay += w*ev.y; az += w*ev.z; aw += w*ev.w;
    }
    float4 r; r.x = ax; r.y = ay; r.z = az; r.w = aw;
    ((float4*)(part + (size_t)(b*8 + sc) * ENC_))[t] = r;
}

__global__ __launch_bounds__(256) void ctx_combine_kernel(
    const float* __restrict__ part, float* __restrict__ ctx_out)
{
    int b = blockIdx.x, t = threadIdx.x;
    float ax = 0.f, ay = 0.f, az = 0.f, aw = 0.f;
    for (int c = 0; c < 8; ++c) {
        float4 p = ((const float4*)(part + (size_t)(b*8 + c) * ENC_))[t];
        ax += p.x; ay += p.y; az += p.z; aw += p.w;
    }
    float4 r; r.x = ax; r.y = ay; r.z = az; r.w = aw;
    ((float4*)(ctx_out + (size_t)b * ENC_))[t] = r;
}

// ---------------- out GEMM: out[b,v] = cat(h1,ctx)[b,:] . out_W[v,:] + out_b[v] ----------------
#define TV  128
#define KC  64
#define TVP 132   // pad: transpose-store 8-way instead of 16-way bank conflict, keeps 16B align
#define CBP 36
__global__ __launch_bounds__(256) void out_gemm_kernel(
    const float* __restrict__ h1, const float* __restrict__ ctx,
    const float* __restrict__ W, const float* __restrict__ bias,
    float* __restrict__ out)
{
    __shared__ float Wt[KC][TVP];   // k-major, 33.8 KB
    __shared__ float Ct[KC][CBP];   // k-major, 9.2 KB
    int v0 = blockIdx.x * TV;
    int t  = threadIdx.x;
    int tv = t & 31;    // v-group: rows v0 + 4*tv .. +3
    int tb = t >> 5;    // b-group: batches 4*tb .. +3
    float acc[4][4] = {};

    for (int kc = 0; kc < K3H; kc += KC) {
        __syncthreads();
        // stage W tile (coalesced global read, transpose to k-major on store)
        #pragma unroll
        for (int i = 0; i < 8; ++i) {
            int f4 = i*256 + t;         // 0..2047
            int r  = f4 >> 4;           // v row 0..127
            int c4 = f4 & 15;           // k float4 idx
            float4 wv = *(const float4*)(W + (size_t)(v0 + r) * K3H + kc + c4*4);
            Wt[c4*4+0][r] = wv.x; Wt[c4*4+1][r] = wv.y;
            Wt[c4*4+2][r] = wv.z; Wt[c4*4+3][r] = wv.w;
        }
        // stage cat tile (k-chunk is homogeneous: kc<512 -> h1, else ctx)
        #pragma unroll
        for (int i = 0; i < 2; ++i) {
            int f4 = i*256 + t;         // 0..511
            int bb = f4 >> 4;           // batch 0..31
            int c4 = f4 & 15;
            int kg = kc + c4*4;
            float4 cv = (kg < H_)
                ? *(const float4*)(h1 + (size_t)bb*H_ + kg)
                : *(const float4*)(ctx + (size_t)bb*ENC_ + (kg - H_));
            Ct[c4*4+0][bb] = cv.x; Ct[c4*4+1][bb] = cv.y;
            Ct[c4*4+2][bb] = cv.z; Ct[c4*4+3][bb] = cv.w;
        }
        __syncthreads();
        #pragma unroll 8
        for (int k = 0; k < KC; ++k) {
            float4 wv = *(const float4*)&Wt[k][tv*4];
            float4 cv = *(const float4*)&Ct[k][tb*4];
            acc[0][0] += wv.x*cv.x; acc[0][1] += wv.x*cv.y; acc[0][2] += wv.x*cv.z; acc[0][3] += wv.x*cv.w;
            acc[1][0] += wv.y*cv.x; acc[1][1] += wv.y*cv.y; acc[1][2] += wv.y*cv.z; acc[1][3] += wv.y*cv.w;
            acc[2][0] += wv.z*cv.x; acc[2][1] += wv.z*cv.y; acc[2][2] += wv.z*cv.z; acc[2][3] += wv.z*cv.w;
            acc[3][0] += wv.w*cv.x; acc[3][1] += wv.w*cv.y; acc[3][2] += wv.w*cv.z; acc[3][3] += wv.w*cv.w;
        }
    }
    #pragma unroll
    for (int i = 0; i < 4; ++i) {
        int v = v0 + tv*4 + i;
        float bo = bias[v];
        #pragma unroll
        for (int j = 0; j < 4; ++j) {
            int bb = tb*4 + j;
            out[(size_t)bb * V_ + v] = acc[i][j] + bo;
        }
    }
}

extern "C" void kernel_launch(void* const* d_in, const int* in_sizes, int n_in,
                              void* d_out, int out_size, void* d_ws, size_t ws_size,
                              hipStream_t stream) {
    const float* x       = (const float*)d_in[0];
    const float* context = (const float*)d_in[1];
    const float* hidden  = (const float*)d_in[2];
    const float* enc     = (const float*)d_in[3];
    const float* attn_W  = (const float*)d_in[4];
    // d_in[5] = attn_b: contributes a per-batch constant to energies -> cancels in softmax
    const float* W_ih0   = (const float*)d_in[6];
    const float* W_hh0   = (const float*)d_in[7];
    const float* b_ih0   = (const float*)d_in[8];
    const float* b_hh0   = (const float*)d_in[9];
    const float* W_ih1   = (const float*)d_in[10];
    const float* W_hh1   = (const float*)d_in[11];
    const float* b_ih1   = (const float*)d_in[12];
    const float* b_hh1   = (const float*)d_in[13];
    const float* out_W   = (const float*)d_in[14];
    const float* out_b   = (const float*)d_in[15];

    float* out = (float*)d_out;
    float* ws  = (float*)d_ws;
    float* h0      = ws + WS_H0;
    float* h1      = ws + WS_H1;
    float* v       = ws + WS_V;
    float* ctxp    = ws + WS_CTXP;
    float* e_attnw = out + ATTN_OFF;   // raw energies then softmax in-place
    float* ctx_out = out + CTX_OFF;
    float* hid_out = out + HID_OFF;

    gru_kernel<GIN, true ><<<4096, 256, 0, stream>>>(x, context, hidden,
        W_ih0, W_hh0, b_ih0, b_hh0, h0, hid_out);
    gru_kernel<H_,  false><<<4096, 256, 0, stream>>>(h0, nullptr, hidden + B_*H_,
        W_ih1, W_hh1, b_ih1, b_hh1, h1, hid_out + B_*H_);
    attn_v_kernel   <<<16,    256, 0, stream>>>(h1, attn_W, v);
    energy_kernel   <<<8192,  256, 0, stream>>>(enc, v, e_attnw);
    softmax_kernel  <<<B_,    256, 0, stream>>>(e_attnw);
    ctx_partial_kernel<<<256, 256, 0, stream>>>(enc, e_attnw, ctxp);
    ctx_combine_kernel<<<B_,  256, 0, stream>>>(ctxp, ctx_out);
    out_gemm_kernel <<<V_/TV, 256, 0, stream>>>(h1, ctx_out, out_W, out_b, out);
}